// Round 10
// baseline (88.148 us; speedup 1.0000x reference)
//
#include <hip/hip_runtime.h>

// Path signature depth-3, path (N=32, L=128, C=48) fp32 — fused single kernel.
//
// *** R10 IS A DIAGNOSTIC ROUND ***
// R4-R9 invariant: kernel ~29 us (total - 46.6 us fill overhead) across five
// structurally different kernels, while VALU/LDS pipe models all say 8-10 us.
// The kernel has been invisible in rocprof top-5 since R6 (the harness's
// 268 MB ws-poison fill at ~41 us outranks it). This round launches the
// IDENTICAL R9 kernel with a 2x duplicated grid (blocks 864..1727 redo
// blocks 0..863, writing identical values — benign duplicate stores) so the
// dispatch is ~58 us and surfaces VGPR_Count / VALUBusy / WRITE_SIZE
// (spill test) / SQ_LDS_BANK_CONFLICT. Also disambiguates overhead:
// total ~= 75.4 + K  =>  K from Delta(total).
//
// Math (unchanged, R5/R9-validated, absmax 0.25):
//   v_t = p[t+1]-p[t], P_t[i] = p[t][i]-p[0][i],
//   G_t = P_t + v_t/2,  R_t = P_t/2 + v_t/6
//   S1 = p[127]-p[0];  S2[i,j] = sum_t G_t[i] v_t[j]
//   S3[i,j,k] = sum_t (a2prefix + R_t[i] v_t[j]) v_t[k]
//   t-split x4 with exact a2-prefix (x) W_q fixup.

#define N_BATCH 32
#define LPATH   128
#define T_STEPS 127
#define C       48
#define C2      2304
#define C3      110592
#define OUT_PER_N (C + C2 + C3)      // 112944
#define PATH_PER_N (LPATH * C)       // 6144
#define GROUPS 27                    // 1728 (i,jg,kc) units / 64 lanes
#define RSLOT 36                     // per-q slots/round: 4jj*8k + 4 a2
#define LDS_FLOATS 6912              // max(v: 6096, reduce: 3*36*64=6912)
#define BLOCKS_REAL (N_BATCH * GROUPS)   // 864
#define DUP 2

__global__ __launch_bounds__(256, 2) void sig_fused(const float* __restrict__ path,
                                                    float* __restrict__ out) {
    __shared__ float lds[LDS_FLOATS];

    int bid = blockIdx.x % BLOCKS_REAL;     // DUP: second copy redoes 0..863
    int n = bid / GROUPS;
    int g = bid - n * GROUPS;
    int tid = threadIdx.x;
    int q = tid >> 6;                // t-segment 0..3
    int lane = tid & 63;

    const float* __restrict__ pb = path + n * PATH_PER_N;

    // ---- stage v = diff(p) into LDS (coalesced float4) ----
    {
        const float4* p4 = (const float4*)pb;
        float4* v4 = (float4*)lds;
        #pragma unroll
        for (int c = 0; c < 6; ++c) {
            int idx = tid + 256 * c;
            if (idx < (T_STEPS * C) / 4) {            // 1524
                float4 a = p4[idx];
                float4 b = p4[idx + C / 4];
                v4[idx] = make_float4(b.x - a.x, b.y - a.y, b.z - a.z, b.w - a.w);
            }
        }
    }
    // S1 (once per batch; duplicate grid copy writes identical values)
    if (g == 0 && tid < C)
        out[(long)n * OUT_PER_N + tid] = pb[(LPATH - 1) * C + tid] - pb[tid];
    __syncthreads();

    // unit U -> (i, jg, kc): U = i*36 + jg*6 + kc ; j = jg*8+[0,8), k = kc*8+[0,8)
    int U = g * 64 + lane;
    int i = U / 36;
    int rr = U - i * 36;
    int jg = rr / 6;
    int kc = rr - jg * 6;

    int T0 = q * 32;
    int T1 = (q == 3) ? T_STEPS : (T0 + 32);

    float Pi = pb[T0 * C + i] - pb[i];   // exact global prefix at segment start
    float a2[8];
    float4 s3[8][2];
    #pragma unroll
    for (int jj = 0; jj < 8; ++jj) {
        a2[jj] = 0.f;
        s3[jj][0] = make_float4(0.f, 0.f, 0.f, 0.f);
        s3[jj][1] = make_float4(0.f, 0.f, 0.f, 0.f);
    }

    // ---- software-pipelined main loop (ping-pong prefetch) ----
    float4 ck0, ck1, cvj0, cvj1;
    float  cvi;
    {
        const float* base = lds + T0 * C;
        ck0  = *(const float4*)(base + kc * 8);
        ck1  = *(const float4*)(base + kc * 8 + 4);
        cvj0 = *(const float4*)(base + jg * 8);
        cvj1 = *(const float4*)(base + jg * 8 + 4);
        cvi  = base[i];
    }

#define SIGCOMPUTE() do {                                               \
        float G = Pi + 0.5f * cvi;                                      \
        float R = 0.5f * Pi + (1.0f / 6.0f) * cvi;                      \
        Pi += cvi;                                                      \
        float vja[8] = {cvj0.x, cvj0.y, cvj0.z, cvj0.w,                 \
                        cvj1.x, cvj1.y, cvj1.z, cvj1.w};                \
        _Pragma("unroll")                                               \
        for (int jj = 0; jj < 8; ++jj) {                                \
            float b_ = a2[jj] + R * vja[jj];                            \
            a2[jj] += G * vja[jj];                                      \
            s3[jj][0].x += b_ * ck0.x;  s3[jj][0].y += b_ * ck0.y;      \
            s3[jj][0].z += b_ * ck0.z;  s3[jj][0].w += b_ * ck0.w;      \
            s3[jj][1].x += b_ * ck1.x;  s3[jj][1].y += b_ * ck1.y;      \
            s3[jj][1].z += b_ * ck1.z;  s3[jj][1].w += b_ * ck1.w;      \
        }                                                               \
    } while (0)

    #pragma unroll 2
    for (int t = T0; t < T1 - 1; ++t) {
        const float* nb = lds + (t + 1) * C;
        float4 nk0  = *(const float4*)(nb + kc * 8);
        float4 nk1  = *(const float4*)(nb + kc * 8 + 4);
        float4 nvj0 = *(const float4*)(nb + jg * 8);
        float4 nvj1 = *(const float4*)(nb + jg * 8 + 4);
        float  nvi  = nb[i];
        SIGCOMPUTE();
        ck0 = nk0; ck1 = nk1; cvj0 = nvj0; cvj1 = nvj1; cvi = nvi;
    }
    SIGCOMPUTE();                    // last t of this segment
#undef SIGCOMPUTE

    // ---- W vectors for the fixup (wave 3 only; L2-hot global reads) ----
    float4 W10, W11, W20, W21, W30, W31;
    if (q == 3) {
        float4 p32a = *(const float4*)(pb + 32 * C + kc * 8);
        float4 p32b = *(const float4*)(pb + 32 * C + kc * 8 + 4);
        float4 p64a = *(const float4*)(pb + 64 * C + kc * 8);
        float4 p64b = *(const float4*)(pb + 64 * C + kc * 8 + 4);
        float4 p96a = *(const float4*)(pb + 96 * C + kc * 8);
        float4 p96b = *(const float4*)(pb + 96 * C + kc * 8 + 4);
        float4 pEa  = *(const float4*)(pb + 127 * C + kc * 8);
        float4 pEb  = *(const float4*)(pb + 127 * C + kc * 8 + 4);
        W10 = make_float4(p64a.x - p32a.x, p64a.y - p32a.y, p64a.z - p32a.z, p64a.w - p32a.w);
        W11 = make_float4(p64b.x - p32b.x, p64b.y - p32b.y, p64b.z - p32b.z, p64b.w - p32b.w);
        W20 = make_float4(p96a.x - p64a.x, p96a.y - p64a.y, p96a.z - p64a.z, p96a.w - p64a.w);
        W21 = make_float4(p96b.x - p64b.x, p96b.y - p64b.y, p96b.z - p64b.z, p96b.w - p64b.w);
        W30 = make_float4(pEa.x - p96a.x, pEa.y - p96a.y, pEa.z - p96a.z, pEa.w - p96a.w);
        W31 = make_float4(pEb.x - p96b.x, pEb.y - p96b.y, pEb.z - p96b.z, pEb.w - p96b.w);
    }

    __syncthreads();                 // all waves done reading v

    // ---- 2 rounds: waves 0-2 deposit 4 jj's, wave 3 combines + stores ----
    long obase = (long)n * OUT_PER_N + C;
    #pragma unroll
    for (int r = 0; r < 2; ++r) {
        if (r) __syncthreads();      // protect previous round's reads
        if (q < 3) {
            float* dst = lds + (q * RSLOT) * 64 + lane;   // lane-major slots
            #pragma unroll
            for (int jjr = 0; jjr < 4; ++jjr) {
                int jj = r * 4 + jjr;
                dst[(jjr * 8 + 0) * 64] = s3[jj][0].x;
                dst[(jjr * 8 + 1) * 64] = s3[jj][0].y;
                dst[(jjr * 8 + 2) * 64] = s3[jj][0].z;
                dst[(jjr * 8 + 3) * 64] = s3[jj][0].w;
                dst[(jjr * 8 + 4) * 64] = s3[jj][1].x;
                dst[(jjr * 8 + 5) * 64] = s3[jj][1].y;
                dst[(jjr * 8 + 6) * 64] = s3[jj][1].z;
                dst[(jjr * 8 + 7) * 64] = s3[jj][1].w;
                dst[(32 + jjr) * 64]    = a2[jj];
            }
        }
        __syncthreads();
        if (q == 3) {
            #pragma unroll
            for (int jjr = 0; jjr < 4; ++jjr) {
                int jj = r * 4 + jjr;
                const float* s0 = lds + (0 * RSLOT) * 64 + lane;
                const float* s1 = lds + (1 * RSLOT) * 64 + lane;
                const float* s2 = lds + (2 * RSLOT) * 64 + lane;
                float a2q0 = s0[(32 + jjr) * 64];
                float a2q1 = s1[(32 + jjr) * 64];
                float a2q2 = s2[(32 + jjr) * 64];
                float pre1 = a2q0;
                float pre2 = a2q0 + a2q1;
                float pre3 = pre2 + a2q2;
                float acc[8];
                #pragma unroll
                for (int c = 0; c < 8; ++c) {
                    int sl = (jjr * 8 + c) * 64;
                    acc[c] = s0[sl] + s1[sl] + s2[sl];
                }
                acc[0] += s3[jj][0].x + pre1 * W10.x + pre2 * W20.x + pre3 * W30.x;
                acc[1] += s3[jj][0].y + pre1 * W10.y + pre2 * W20.y + pre3 * W30.y;
                acc[2] += s3[jj][0].z + pre1 * W10.z + pre2 * W20.z + pre3 * W30.z;
                acc[3] += s3[jj][0].w + pre1 * W10.w + pre2 * W20.w + pre3 * W30.w;
                acc[4] += s3[jj][1].x + pre1 * W11.x + pre2 * W21.x + pre3 * W31.x;
                acc[5] += s3[jj][1].y + pre1 * W11.y + pre2 * W21.y + pre3 * W31.y;
                acc[6] += s3[jj][1].z + pre1 * W11.z + pre2 * W21.z + pre3 * W31.z;
                acc[7] += s3[jj][1].w + pre1 * W11.w + pre2 * W21.w + pre3 * W31.w;

                float* dst = out + obase + C2 + (long)(i * C + jg * 8 + jj) * C + kc * 8;
                *(float4*)(dst)     = make_float4(acc[0], acc[1], acc[2], acc[3]);
                *(float4*)(dst + 4) = make_float4(acc[4], acc[5], acc[6], acc[7]);
                if (kc == 0)
                    out[obase + i * C + jg * 8 + jj] = pre3 + a2[jj];   // S2
            }
        }
    }
}

extern "C" void kernel_launch(void* const* d_in, const int* in_sizes, int n_in,
                              void* d_out, int out_size, void* d_ws, size_t ws_size,
                              hipStream_t stream) {
    const float* path = (const float*)d_in[0];
    float* out = (float*)d_out;
    (void)d_ws; (void)ws_size;

    // DUP x grid: diagnostic duplication (identical values written twice)
    sig_fused<<<BLOCKS_REAL * DUP, 256, 0, stream>>>(path, out);
}

// Round 11
// 75.245 us; speedup vs baseline: 1.1715x; 1.1715x over previous
//
#include <hip/hip_runtime.h>

// Path signature depth-3, path (N=32, L=128, C=48) fp32 — fused single kernel.
//
// Math (R5/R9-validated, absmax 0.25):
//   v_t = p[t+1]-p[t], P_t[i] = p[t][i]-p[0][i],
//   G_t = P_t + v_t/2,  R_t = P_t/2 + v_t/6
//   S1 = p[127]-p[0];  S2[i,j] = sum_t G_t[i] v_t[j]   (register prefix a2)
//   S3[i,j,k] = sum_t (a2prefix + R_t[i] v_t[j]) v_t[k]
//   t-split x4 (32/32/32/31), Pi seeded globally per segment; exact fixup
//   S3 = sum_q [S3loc_q + a2pre_q (x) W_q], W_q = p[seg_end]-p[seg_start].
//
// R11 (R10 diagnostic post-mortem): DUP=2 gave total 75.4->88.1 us =>
// kernel K ~= 12.7 us, fixed harness overhead ~= 63 us (ws re-poison fill
// dominates). Back-solved VALUBusy ~57% -> VALU largest consumer. This round:
// pack the 64 s3 FMAs/iter into 32 v_pk_fma_f32 (gfx950 packed fp32, 2x rate)
// via ext_vector_type(2) + __builtin_elementwise_fma. Model: per-iter VALU
// 166 -> 102 cyc, kernel -> ~10 us. Grid/layout identical to R9 (DUP reverted).

#define N_BATCH 32
#define LPATH   128
#define T_STEPS 127
#define C       48
#define C2      2304
#define C3      110592
#define OUT_PER_N (C + C2 + C3)      // 112944
#define PATH_PER_N (LPATH * C)       // 6144
#define GROUPS 27                    // 1728 (i,jg,kc) units / 64 lanes
#define RSLOT 36                     // per-q slots/round: 4jj*8k + 4 a2
#define LDS_FLOATS 6912              // max(v: 6096, reduce: 3*36*64=6912)

typedef float f32x2 __attribute__((ext_vector_type(2)));

__global__ __launch_bounds__(256, 2) void sig_fused(const float* __restrict__ path,
                                                    float* __restrict__ out) {
    __shared__ float lds[LDS_FLOATS];

    int bid = blockIdx.x;
    int n = bid / GROUPS;
    int g = bid - n * GROUPS;
    int tid = threadIdx.x;
    int q = tid >> 6;                // t-segment 0..3
    int lane = tid & 63;

    const float* __restrict__ pb = path + n * PATH_PER_N;

    // ---- stage v = diff(p) into LDS (coalesced float4) ----
    {
        const float4* p4 = (const float4*)pb;
        float4* v4 = (float4*)lds;
        #pragma unroll
        for (int c = 0; c < 6; ++c) {
            int idx = tid + 256 * c;
            if (idx < (T_STEPS * C) / 4) {            // 1524
                float4 a = p4[idx];
                float4 b = p4[idx + C / 4];
                v4[idx] = make_float4(b.x - a.x, b.y - a.y, b.z - a.z, b.w - a.w);
            }
        }
    }
    // S1 (once per batch), overlapped with staging
    if (g == 0 && tid < C)
        out[(long)n * OUT_PER_N + tid] = pb[(LPATH - 1) * C + tid] - pb[tid];
    __syncthreads();

    // unit U -> (i, jg, kc): U = i*36 + jg*6 + kc ; j = jg*8+[0,8), k = kc*8+[0,8)
    int U = g * 64 + lane;
    int i = U / 36;
    int rr = U - i * 36;
    int jg = rr / 6;
    int kc = rr - jg * 6;

    int T0 = q * 32;
    int T1 = (q == 3) ? T_STEPS : (T0 + 32);

    float Pi = pb[T0 * C + i] - pb[i];   // exact global prefix at segment start
    float a2[8];
    f32x2 s3[8][4];                      // packed k-pairs: [jj][kpair]
    #pragma unroll
    for (int jj = 0; jj < 8; ++jj) {
        a2[jj] = 0.f;
        #pragma unroll
        for (int p = 0; p < 4; ++p) s3[jj][p] = (f32x2){0.f, 0.f};
    }

    // ---- software-pipelined main loop (ping-pong prefetch) ----
    float4 ck0, ck1, cvj0, cvj1;
    float  cvi;
    {
        const float* base = lds + T0 * C;
        ck0  = *(const float4*)(base + kc * 8);
        ck1  = *(const float4*)(base + kc * 8 + 4);
        cvj0 = *(const float4*)(base + jg * 8);
        cvj1 = *(const float4*)(base + jg * 8 + 4);
        cvi  = base[i];
    }

#define SIGCOMPUTE() do {                                               \
        float G = Pi + 0.5f * cvi;                                      \
        float R = 0.5f * Pi + (1.0f / 6.0f) * cvi;                      \
        Pi += cvi;                                                      \
        f32x2 kk0 = {ck0.x, ck0.y};                                     \
        f32x2 kk1 = {ck0.z, ck0.w};                                     \
        f32x2 kk2 = {ck1.x, ck1.y};                                     \
        f32x2 kk3 = {ck1.z, ck1.w};                                     \
        float vja[8] = {cvj0.x, cvj0.y, cvj0.z, cvj0.w,                 \
                        cvj1.x, cvj1.y, cvj1.z, cvj1.w};                \
        _Pragma("unroll")                                               \
        for (int jj = 0; jj < 8; ++jj) {                                \
            float b_ = __builtin_fmaf(R, vja[jj], a2[jj]);              \
            a2[jj] = __builtin_fmaf(G, vja[jj], a2[jj]);                \
            f32x2 bb = {b_, b_};                                        \
            s3[jj][0] = __builtin_elementwise_fma(bb, kk0, s3[jj][0]);  \
            s3[jj][1] = __builtin_elementwise_fma(bb, kk1, s3[jj][1]);  \
            s3[jj][2] = __builtin_elementwise_fma(bb, kk2, s3[jj][2]);  \
            s3[jj][3] = __builtin_elementwise_fma(bb, kk3, s3[jj][3]);  \
        }                                                               \
    } while (0)

    #pragma unroll 2
    for (int t = T0; t < T1 - 1; ++t) {
        const float* nb = lds + (t + 1) * C;
        float4 nk0  = *(const float4*)(nb + kc * 8);
        float4 nk1  = *(const float4*)(nb + kc * 8 + 4);
        float4 nvj0 = *(const float4*)(nb + jg * 8);
        float4 nvj1 = *(const float4*)(nb + jg * 8 + 4);
        float  nvi  = nb[i];
        SIGCOMPUTE();
        ck0 = nk0; ck1 = nk1; cvj0 = nvj0; cvj1 = nvj1; cvi = nvi;
    }
    SIGCOMPUTE();                    // last t of this segment
#undef SIGCOMPUTE

    // ---- W vectors for the fixup (wave 3 only; L2-hot global reads) ----
    float4 W10, W11, W20, W21, W30, W31;
    if (q == 3) {
        float4 p32a = *(const float4*)(pb + 32 * C + kc * 8);
        float4 p32b = *(const float4*)(pb + 32 * C + kc * 8 + 4);
        float4 p64a = *(const float4*)(pb + 64 * C + kc * 8);
        float4 p64b = *(const float4*)(pb + 64 * C + kc * 8 + 4);
        float4 p96a = *(const float4*)(pb + 96 * C + kc * 8);
        float4 p96b = *(const float4*)(pb + 96 * C + kc * 8 + 4);
        float4 pEa  = *(const float4*)(pb + 127 * C + kc * 8);
        float4 pEb  = *(const float4*)(pb + 127 * C + kc * 8 + 4);
        W10 = make_float4(p64a.x - p32a.x, p64a.y - p32a.y, p64a.z - p32a.z, p64a.w - p32a.w);
        W11 = make_float4(p64b.x - p32b.x, p64b.y - p32b.y, p64b.z - p32b.z, p64b.w - p32b.w);
        W20 = make_float4(p96a.x - p64a.x, p96a.y - p64a.y, p96a.z - p64a.z, p96a.w - p64a.w);
        W21 = make_float4(p96b.x - p64b.x, p96b.y - p64b.y, p96b.z - p64b.z, p96b.w - p64b.w);
        W30 = make_float4(pEa.x - p96a.x, pEa.y - p96a.y, pEa.z - p96a.z, pEa.w - p96a.w);
        W31 = make_float4(pEb.x - p96b.x, pEb.y - p96b.y, pEb.z - p96b.z, pEb.w - p96b.w);
    }

    __syncthreads();                 // all waves done reading v

    // ---- 2 rounds: waves 0-2 deposit 4 jj's, wave 3 combines + stores ----
    long obase = (long)n * OUT_PER_N + C;
    #pragma unroll
    for (int r = 0; r < 2; ++r) {
        if (r) __syncthreads();      // protect previous round's reads
        if (q < 3) {
            float* dst = lds + (q * RSLOT) * 64 + lane;   // lane-major slots
            #pragma unroll
            for (int jjr = 0; jjr < 4; ++jjr) {
                int jj = r * 4 + jjr;
                dst[(jjr * 8 + 0) * 64] = s3[jj][0][0];
                dst[(jjr * 8 + 1) * 64] = s3[jj][0][1];
                dst[(jjr * 8 + 2) * 64] = s3[jj][1][0];
                dst[(jjr * 8 + 3) * 64] = s3[jj][1][1];
                dst[(jjr * 8 + 4) * 64] = s3[jj][2][0];
                dst[(jjr * 8 + 5) * 64] = s3[jj][2][1];
                dst[(jjr * 8 + 6) * 64] = s3[jj][3][0];
                dst[(jjr * 8 + 7) * 64] = s3[jj][3][1];
                dst[(32 + jjr) * 64]    = a2[jj];
            }
        }
        __syncthreads();
        if (q == 3) {
            #pragma unroll
            for (int jjr = 0; jjr < 4; ++jjr) {
                int jj = r * 4 + jjr;
                const float* s0 = lds + (0 * RSLOT) * 64 + lane;
                const float* s1 = lds + (1 * RSLOT) * 64 + lane;
                const float* s2 = lds + (2 * RSLOT) * 64 + lane;
                float a2q0 = s0[(32 + jjr) * 64];
                float a2q1 = s1[(32 + jjr) * 64];
                float a2q2 = s2[(32 + jjr) * 64];
                float pre1 = a2q0;
                float pre2 = a2q0 + a2q1;
                float pre3 = pre2 + a2q2;
                float acc[8];
                #pragma unroll
                for (int c = 0; c < 8; ++c) {
                    int sl = (jjr * 8 + c) * 64;
                    acc[c] = s0[sl] + s1[sl] + s2[sl];
                }
                acc[0] += s3[jj][0][0] + pre1 * W10.x + pre2 * W20.x + pre3 * W30.x;
                acc[1] += s3[jj][0][1] + pre1 * W10.y + pre2 * W20.y + pre3 * W30.y;
                acc[2] += s3[jj][1][0] + pre1 * W10.z + pre2 * W20.z + pre3 * W30.z;
                acc[3] += s3[jj][1][1] + pre1 * W10.w + pre2 * W20.w + pre3 * W30.w;
                acc[4] += s3[jj][2][0] + pre1 * W11.x + pre2 * W21.x + pre3 * W31.x;
                acc[5] += s3[jj][2][1] + pre1 * W11.y + pre2 * W21.y + pre3 * W31.y;
                acc[6] += s3[jj][3][0] + pre1 * W11.z + pre2 * W21.z + pre3 * W31.z;
                acc[7] += s3[jj][3][1] + pre1 * W11.w + pre2 * W21.w + pre3 * W31.w;

                float* dst = out + obase + C2 + (long)(i * C + jg * 8 + jj) * C + kc * 8;
                *(float4*)(dst)     = make_float4(acc[0], acc[1], acc[2], acc[3]);
                *(float4*)(dst + 4) = make_float4(acc[4], acc[5], acc[6], acc[7]);
                if (kc == 0)
                    out[obase + i * C + jg * 8 + jj] = pre3 + a2[jj];   // S2
            }
        }
    }
}

extern "C" void kernel_launch(void* const* d_in, const int* in_sizes, int n_in,
                              void* d_out, int out_size, void* d_ws, size_t ws_size,
                              hipStream_t stream) {
    const float* path = (const float*)d_in[0];
    float* out = (float*)d_out;
    (void)d_ws; (void)ws_size;

    sig_fused<<<N_BATCH * GROUPS, 256, 0, stream>>>(path, out);
}